// Round 2
// baseline (26198.962 us; speedup 1.0000x reference)
//
#include <hip/hip_runtime.h>
#include <hip/hip_cooperative_groups.h>
#include <math.h>

namespace cg = cooperative_groups;

#define NB 128      // batch
#define NT 64       // timesteps
#define NI 512      // input dim
#define NH 1024     // hidden dim
#define NO 512      // output dim
#define PONDOFF (NB*NT*NO)

// Per-group (32-block) barrier: monotonic generation, arrival flags in ws.
// threadfence (agent release of all prior plain stores) -> arrival store
// (RELEASE/AGENT) -> wave0 polls all 32 flags (ACQUIRE/AGENT) -> syncthreads.
__device__ __forceinline__ void group_barrier(unsigned* arr, int lb, unsigned gen, int tid)
{
    __threadfence();
    __syncthreads();
    if (tid == 0)
        __hip_atomic_store(&arr[lb], gen, __ATOMIC_RELEASE, __HIP_MEMORY_SCOPE_AGENT);
    if (tid < 32) {
        while (__hip_atomic_load(&arr[tid], __ATOMIC_ACQUIRE, __HIP_MEMORY_SCOPE_AGENT) < gen)
            __builtin_amdgcn_s_sleep(1);
    }
    __syncthreads();
}

// 256 blocks x 1024 threads. 8 groups x 32 blocks; group owns 16 batch rows.
// Thread tile: 2 rows x 2 cols x (1/8 of k). All reductions in-wave (shfl_xor).
// Wave w: rg = w>>1 (row pair), cpo = w&1 (col octet). Lane: cpl = lane&7, ks = lane>>3.
__global__ void __launch_bounds__(1024, 1)
arnn_coop(const float* __restrict__ x, const float* __restrict__ s0,
          const float* __restrict__ w_ih, const float* __restrict__ w_hh,
          const float* __restrict__ b_ih, const float* __restrict__ b_hh,
          const float* __restrict__ w_halt, const float* __restrict__ b_halt,
          const float* __restrict__ w_out, const float* __restrict__ b_out,
          float* __restrict__ out, float* __restrict__ ws)
{
    cg::grid_group grid = cg::this_grid();
    const int tid = threadIdx.x;
    const int bid = blockIdx.x;
    const int gid = bid * 1024 + tid;

    // ws layout (floats)
    float* whhT  = ws;                    // [NH][NH]  whhT[k*NH+j] = w_hh[j][k]
    float* wihT  = whhT + NH*NH;          // [NI][NH]  wihT[i*NH+j] = w_ih[j][1+i]
    float* woT   = wihT + NI*NH;          // [NH][NO]  woT[j*NO+o]  = w_out[o][j]
    float* w0v   = woT  + NH*NO;          // [NH]      w_ih[j][0]
    float* hbuf  = w0v  + NH;             // [2][NB][NH] step-parity h double buffer
    float* habuf = hbuf + 2*NB*NH;        // [2][NB][NH] timestep-parity h_acc
    float* haltA = habuf+ 2*NB*NH;        // [8][3][16] rotating halt-dot accumulators
    unsigned* arrA = (unsigned*)(haltA + 8*3*16);   // [8][32] barrier flags

    // ---- phase 0: transpose weights, zero halt slots + barrier flags
    for (int e = gid; e < NH*NH; e += 256*1024) { int k = e>>10, j = e&1023; whhT[e] = w_hh[j*NH + k]; }
    for (int e = gid; e < NI*NH; e += 256*1024) { int i = e>>10, j = e&1023; wihT[e] = w_ih[j*(NI+1) + 1 + i]; }
    for (int e = gid; e < NH*NO; e += 256*1024) { int j = e>>9,  o = e&511;  woT[e]  = w_out[o*NH + j]; }
    if (gid < NH)     w0v[gid]   = w_ih[gid*(NI+1)];
    if (gid < 8*3*16) haltA[gid] = 0.0f;
    if (gid < 256)    arrA[gid]  = 0u;
    grid.sync();

    const int gp = bid >> 5;              // group 0..7 (rows gp*16..gp*16+15)
    const int lb = bid & 31;              // block within group (cols lb*32..lb*32+31)
    float*    ghalt = haltA + gp*48;
    unsigned* arr   = arrA  + gp*32;

    const int w    = tid >> 6;            // wave 0..15
    const int lane = tid & 63;
    const int rg   = w >> 1;              // row pair 0..7
    const int cpo  = w & 1;               // col octet 0..1
    const int cpl  = lane & 7;            // col pair in octet
    const int ks   = lane >> 3;           // k-slice 0..7
    const int b0   = gp*16 + rg*2, b1 = b0 + 1;
    const int j    = lb*32 + (cpo*8 + cpl)*2;

    const float wh0 = w_halt[j], wh1 = w_halt[j+1];
    const float bh  = b_halt[0];
    const bool  k0  = (ks == 0);
    const float bias0 = k0 ? (b_ih[j]   + b_hh[j])   : 0.0f;
    const float bias1 = k0 ? (b_ih[j+1] + b_hh[j+1]) : 0.0f;
    const float w0a   = k0 ? w0v[j]   : 0.0f;
    const float w0b   = k0 ? w0v[j+1] : 0.0f;

    // epilogue mapping: wave = row, lane = (ocol 0..15, kquarter 0..3)
    const int   eo = lb*16 + (lane & 15);
    const int   eq = lane >> 4;
    const int   eb = gp*16 + w;
    const float bo = b_out[eo];

    __shared__ float s_cum[16];
    __shared__ int   s_n[16];
    __shared__ unsigned char s_act[16];
    __shared__ int   s_cnt;
    __shared__ float s_hp[16][2];         // per-wave halt-dot partials (2 rows)

    unsigned gen = 0;
    int g = 0;                            // group-local step counter -> halt slot rotation
    for (int t = 0; t < NT; ++t) {
        // -------- x-part partials (persist across ponder steps) --------
        float xw00 = bias0, xw01 = bias1, xw10 = bias0, xw11 = bias1;
        {
            const float* xr0 = x + (b0*NT + t)*NI + ks*64;
            const float* xr1 = x + (b1*NT + t)*NI + ks*64;
            const float* wp  = wihT + (ks*64)*NH + j;
            for (int i = 0; i < 64; i += 4) {
                const float4 x0 = *(const float4*)(xr0 + i);
                const float4 x1 = *(const float4*)(xr1 + i);
                const float2 wa = *(const float2*)(wp + (i  )*NH);
                const float2 wb = *(const float2*)(wp + (i+1)*NH);
                const float2 wc = *(const float2*)(wp + (i+2)*NH);
                const float2 wd = *(const float2*)(wp + (i+3)*NH);
                xw00 += x0.x*wa.x + x0.y*wb.x + x0.z*wc.x + x0.w*wd.x;
                xw01 += x0.x*wa.y + x0.y*wb.y + x0.z*wc.y + x0.w*wd.y;
                xw10 += x1.x*wa.x + x1.y*wb.x + x1.z*wc.x + x1.w*wd.x;
                xw11 += x1.x*wa.y + x1.y*wb.y + x1.z*wc.y + x1.w*wd.y;
            }
        }
        // -------- main step: hh matmul + tanh --------
        {
            float a00 = xw00 + w0a, a01 = xw01 + w0b;
            float a10 = xw10 + w0a, a11 = xw11 + w0b;
            const float* hcb = (t == 0) ? s0 : (habuf + ((t-1)&1)*(NB*NH));
            const float* h0p = hcb + b0*NH + ks*128;
            const float* h1p = hcb + b1*NH + ks*128;
            const float* wp  = whhT + (ks*128)*NH + j;
            for (int k = 0; k < 128; k += 4) {
                const float4 h0 = *(const float4*)(h0p + k);
                const float4 h1 = *(const float4*)(h1p + k);
                const float2 wa = *(const float2*)(wp + (k  )*NH);
                const float2 wb = *(const float2*)(wp + (k+1)*NH);
                const float2 wc = *(const float2*)(wp + (k+2)*NH);
                const float2 wd = *(const float2*)(wp + (k+3)*NH);
                a00 += h0.x*wa.x + h0.y*wb.x + h0.z*wc.x + h0.w*wd.x;
                a01 += h0.x*wa.y + h0.y*wb.y + h0.z*wc.y + h0.w*wd.y;
                a10 += h1.x*wa.x + h1.y*wb.x + h1.z*wc.x + h1.w*wd.x;
                a11 += h1.x*wa.y + h1.y*wb.y + h1.z*wc.y + h1.w*wd.y;
            }
            a00 += __shfl_xor(a00, 8); a00 += __shfl_xor(a00, 16); a00 += __shfl_xor(a00, 32);
            a01 += __shfl_xor(a01, 8); a01 += __shfl_xor(a01, 16); a01 += __shfl_xor(a01, 32);
            a10 += __shfl_xor(a10, 8); a10 += __shfl_xor(a10, 16); a10 += __shfl_xor(a10, 32);
            a11 += __shfl_xor(a11, 8); a11 += __shfl_xor(a11, 16); a11 += __shfl_xor(a11, 32);
            const float h00 = tanhf(a00), h01 = tanhf(a01);
            const float h10 = tanhf(a10), h11 = tanhf(a11);
            if (k0) {
                float* hw0 = hbuf + b0*NH + j;                         // slot 0
                float* hw1 = hbuf + b1*NH + j;
                hw0[0] = h00; hw0[1] = h01; hw1[0] = h10; hw1[1] = h11;
                float* ha0 = habuf + (t&1)*(NB*NH) + b0*NH + j;        // h_acc := h
                float* ha1 = habuf + (t&1)*(NB*NH) + b1*NH + j;
                ha0[0] = h00; ha0[1] = h01; ha1[0] = h10; ha1[1] = h11;
                float p0 = h00*wh0 + h01*wh1;
                float p1 = h10*wh0 + h11*wh1;
                p0 += __shfl_xor(p0, 1); p0 += __shfl_xor(p0, 2); p0 += __shfl_xor(p0, 4);
                p1 += __shfl_xor(p1, 1); p1 += __shfl_xor(p1, 2); p1 += __shfl_xor(p1, 4);
                if (cpl == 0) { s_hp[w][0] = p0; s_hp[w][1] = p1; }
            }
        }
        __syncthreads();
        if (tid < 16) {   // one agent atomic per row per block
            const float part = s_hp[(tid>>1)*2][tid&1] + s_hp[(tid>>1)*2+1][tid&1];
            atomicAdd(&ghalt[(g%3)*16 + tid], part);
        }
        ++gen; group_barrier(arr, lb, gen, tid);
        // -------- update after main (identical in all 32 blocks) --------
        if (tid == 0) s_cnt = 0;
        __syncthreads();
        if (tid < 16) {
            const float z = __hip_atomic_load(&ghalt[(g%3)*16 + tid], __ATOMIC_RELAXED, __HIP_MEMORY_SCOPE_AGENT) + bh;
            const float p = 1.0f / (1.0f + expf(-z));
            s_cum[tid] = p;
            s_n[tid]   = 1;
            const bool a = (p < 0.99f);
            s_act[tid] = a ? 1 : 0;
            if (a) atomicAdd(&s_cnt, 1);
            if (lb == 0) out[PONDOFF + (gp*16 + tid)*NT + t] = a ? 0.0f : 2.0f;
            __hip_atomic_store(&ghalt[((g+2)%3)*16 + tid], 0.0f, __ATOMIC_RELAXED, __HIP_MEMORY_SCOPE_AGENT);
        }
        __syncthreads();
        int any = s_cnt;
        ++g;
        // -------- ponder steps --------
        for (int s = 1; s <= 11 && any; ++s) {
            const int act0 = s_act[rg*2], act1 = s_act[rg*2 + 1];
            if (act0 | act1) {
                float c00 = xw00, c01 = xw01, c10 = xw10, c11 = xw11;  // no ones-column term
                const float* hcb = hbuf + ((s-1)&1)*(NB*NH);
                const float* h0p = hcb + b0*NH + ks*128;
                const float* h1p = hcb + b1*NH + ks*128;
                const float* wp  = whhT + (ks*128)*NH + j;
                for (int k = 0; k < 128; k += 4) {
                    const float4 h0 = *(const float4*)(h0p + k);
                    const float4 h1 = *(const float4*)(h1p + k);
                    const float2 wa = *(const float2*)(wp + (k  )*NH);
                    const float2 wb = *(const float2*)(wp + (k+1)*NH);
                    const float2 wc = *(const float2*)(wp + (k+2)*NH);
                    const float2 wd = *(const float2*)(wp + (k+3)*NH);
                    c00 += h0.x*wa.x + h0.y*wb.x + h0.z*wc.x + h0.w*wd.x;
                    c01 += h0.x*wa.y + h0.y*wb.y + h0.z*wc.y + h0.w*wd.y;
                    c10 += h1.x*wa.x + h1.y*wb.x + h1.z*wc.x + h1.w*wd.x;
                    c11 += h1.x*wa.y + h1.y*wb.y + h1.z*wc.y + h1.w*wd.y;
                }
                c00 += __shfl_xor(c00, 8); c00 += __shfl_xor(c00, 16); c00 += __shfl_xor(c00, 32);
                c01 += __shfl_xor(c01, 8); c01 += __shfl_xor(c01, 16); c01 += __shfl_xor(c01, 32);
                c10 += __shfl_xor(c10, 8); c10 += __shfl_xor(c10, 16); c10 += __shfl_xor(c10, 32);
                c11 += __shfl_xor(c11, 8); c11 += __shfl_xor(c11, 16); c11 += __shfl_xor(c11, 32);
                const float g00 = tanhf(c00), g01 = tanhf(c01);
                const float g10 = tanhf(c10), g11 = tanhf(c11);
                if (k0) {
                    float p0 = 0.0f, p1 = 0.0f;
                    if (act0) {
                        float* hw0 = hbuf + (s&1)*(NB*NH) + b0*NH + j;
                        hw0[0] = g00; hw0[1] = g01;
                        float* ha0 = habuf + (t&1)*(NB*NH) + b0*NH + j;
                        ha0[0] += g00; ha0[1] += g01;
                        p0 = g00*wh0 + g01*wh1;
                    }
                    if (act1) {
                        float* hw1 = hbuf + (s&1)*(NB*NH) + b1*NH + j;
                        hw1[0] = g10; hw1[1] = g11;
                        float* ha1 = habuf + (t&1)*(NB*NH) + b1*NH + j;
                        ha1[0] += g10; ha1[1] += g11;
                        p1 = g10*wh0 + g11*wh1;
                    }
                    p0 += __shfl_xor(p0, 1); p0 += __shfl_xor(p0, 2); p0 += __shfl_xor(p0, 4);
                    p1 += __shfl_xor(p1, 1); p1 += __shfl_xor(p1, 2); p1 += __shfl_xor(p1, 4);
                    if (cpl == 0) { s_hp[w][0] = p0; s_hp[w][1] = p1; }
                }
            }
            __syncthreads();
            if (tid < 16) {
                if (s_act[tid]) {
                    const float part = s_hp[(tid>>1)*2][tid&1] + s_hp[(tid>>1)*2+1][tid&1];
                    atomicAdd(&ghalt[(g%3)*16 + tid], part);
                }
            }
            ++gen; group_barrier(arr, lb, gen, tid);
            if (tid == 0) s_cnt = 0;
            __syncthreads();
            if (tid < 16) {
                if (s_act[tid]) {
                    const float z = __hip_atomic_load(&ghalt[(g%3)*16 + tid], __ATOMIC_RELAXED, __HIP_MEMORY_SCOPE_AGENT) + bh;
                    const float p = 1.0f / (1.0f + expf(-z));
                    const float c = s_cum[tid] + p;
                    s_cum[tid] = c;
                    s_n[tid] += 1;
                    s_act[tid] = (c < 0.99f) ? 1 : 0;
                }
                if (s_act[tid]) atomicAdd(&s_cnt, 1);
                __hip_atomic_store(&ghalt[((g+2)%3)*16 + tid], 0.0f, __ATOMIC_RELAXED, __HIP_MEMORY_SCOPE_AGENT);
            }
            __syncthreads();
            any = s_cnt;
            ++g;
        }
        // -------- epilogue: out = h_acc @ W_out^T + n*b_out --------
        {
            const float* ha = habuf + (t&1)*(NB*NH) + eb*NH + eq*256;
            const float* wq = woT + (eq*256)*NO + eo;
            float acc = 0.0f;
            for (int jj = 0; jj < 256; jj += 4) {
                const float4 hv = *(const float4*)(ha + jj);
                acc += hv.x*wq[(jj  )*NO] + hv.y*wq[(jj+1)*NO]
                     + hv.z*wq[(jj+2)*NO] + hv.w*wq[(jj+3)*NO];
            }
            acc += __shfl_xor(acc, 16); acc += __shfl_xor(acc, 32);
            if (eq == 0) out[(eb*NT + t)*NO + eo] = acc + (float)s_n[w]*bo;
        }
        // no barrier needed: next main writes habuf[(t+1)&1] (other parity) and
        // hbuf slot 0 (unread until after the next main's barrier); halt slot
        // rotation (3 slots) keeps adds/zeros separated by >=1 barrier.
    }
}

extern "C" void kernel_launch(void* const* d_in, const int* in_sizes, int n_in,
                              void* d_out, int out_size, void* d_ws, size_t ws_size,
                              hipStream_t stream) {
    const float* x      = (const float*)d_in[0];
    const float* s0     = (const float*)d_in[1];
    const float* w_ih   = (const float*)d_in[2];
    const float* w_hh   = (const float*)d_in[3];
    const float* b_ih   = (const float*)d_in[4];
    const float* b_hh   = (const float*)d_in[5];
    const float* w_halt = (const float*)d_in[6];
    const float* b_halt = (const float*)d_in[7];
    const float* w_out  = (const float*)d_in[8];
    const float* b_out  = (const float*)d_in[9];
    float* out = (float*)d_out;
    float* ws  = (float*)d_ws;

    void* args[] = { (void*)&x, (void*)&s0, (void*)&w_ih, (void*)&w_hh,
                     (void*)&b_ih, (void*)&b_hh, (void*)&w_halt, (void*)&b_halt,
                     (void*)&w_out, (void*)&b_out, (void*)&out, (void*)&ws };
    hipLaunchCooperativeKernel((void*)arnn_coop, dim3(256), dim3(1024), args, 0, stream);
}

// Round 3
// 9567.491 us; speedup vs baseline: 2.7383x; 2.7383x over previous
//
#include <hip/hip_runtime.h>
#include <hip/hip_cooperative_groups.h>
#include <math.h>

namespace cg = cooperative_groups;

#define NB 128      // batch
#define NT 64       // timesteps
#define NI 512      // input dim
#define NH 1024     // hidden dim
#define NO 512      // output dim
#define PONDOFF (NB*NT*NO)

// dynamic LDS: [1024][32] w_hh column-slice, XOR-swizzled, 128 KB
extern __shared__ float smem[];

// Per-group (32-block) barrier. Release = RELEASE atomic flag store (waitcnt +
// buffer_wbl2 + store). Poll = RELAXED loads (no cache maintenance!) with a
// fetch_add(0) fallback every 64 polls (RMW executes at coherence point ->
// guaranteed progress even if relaxed loads could hit a stale L2 line).
// One ACQUIRE fence (single buffer_inv) after the barrier completes.
__device__ __forceinline__ void group_barrier(unsigned* arr, int lb, unsigned gen, int tid)
{
    __syncthreads();   // compiler drains each wave's vmem before s_barrier
    if (tid == 0)
        __hip_atomic_store(&arr[lb*16], gen, __ATOMIC_RELEASE, __HIP_MEMORY_SCOPE_AGENT);
    if (tid < 32) {
        int it = 0;
        for (;;) {
            unsigned v;
            if ((++it & 63) == 0)
                v = __hip_atomic_fetch_add(&arr[tid*16], 0u, __ATOMIC_RELAXED, __HIP_MEMORY_SCOPE_AGENT);
            else
                v = __hip_atomic_load(&arr[tid*16], __ATOMIC_RELAXED, __HIP_MEMORY_SCOPE_AGENT);
            if (v >= gen) break;
            __builtin_amdgcn_s_sleep(1);
        }
    }
    __syncthreads();
    __builtin_amdgcn_fence(__ATOMIC_ACQUIRE, "agent");   // one buffer_inv
}

// 256 blocks x 1024 threads. 8 groups x 32 blocks; group owns 16 batch rows,
// block owns a 32-col slice. Wave w: rq=w>>2 (row quad), co=w&3 (col octet).
// Lane: up=lane&3 (col pair in octet), ks=lane>>2 (k-slice of 64).
// Thread: 4 rows x 2 cols x 64 k; full-k reduced in-wave (shfl_xor 4..32).
__global__ void __launch_bounds__(1024, 1)
arnn_coop(const float* __restrict__ x, const float* __restrict__ s0,
          const float* __restrict__ w_ih, const float* __restrict__ w_hh,
          const float* __restrict__ b_ih, const float* __restrict__ b_hh,
          const float* __restrict__ w_halt, const float* __restrict__ b_halt,
          const float* __restrict__ w_out, const float* __restrict__ b_out,
          float* __restrict__ out, float* __restrict__ ws)
{
    cg::grid_group grid = cg::this_grid();
    const int tid = threadIdx.x;
    const int bid = blockIdx.x;
    const int gid = bid * 1024 + tid;

    // ws layout (floats)
    float* wihT  = ws;                       // [NI][NH]  wihT[i*NH+j] = w_ih[j][1+i]
    float* hbuf  = wihT + NI*NH;             // [2][NB][NH] step-parity h double buffer
    float* habuf = hbuf + 2*NB*NH;           // [2][NB][NH] timestep-parity h_acc
    float* haltA = habuf + 2*NB*NH;          // [8][3][16][16] halt accs, 64B/row pad
    unsigned* arrA = (unsigned*)(haltA + 8*3*16*16);  // [8][32][16] flags, 64B pad

    const int gp = bid >> 5, lb = bid & 31;

    // ---- phase 0 ----
    for (int e = gid; e < NI*NH; e += 256*1024) {
        const int i = e >> 10, jj = e & 1023;
        wihT[e] = w_ih[jj*(NI+1) + 1 + i];
    }
    if (gid < 8*3*16*16)
        __hip_atomic_store(&haltA[gid], 0.0f, __ATOMIC_RELAXED, __HIP_MEMORY_SCOPE_AGENT);
    if (gid < 8*32*16)
        __hip_atomic_store(&arrA[gid], 0u, __ATOMIC_RELAXED, __HIP_MEMORY_SCOPE_AGENT);
    // stage this block's w_hh column slice into LDS, XOR-swizzled:
    // element (k, j) at float offset k*32 + ((j>>1)^((k>>6)&15))*2 + (j&1)
    for (int e = tid; e < 1024*32; e += 1024) {
        const int k = e & 1023, jj = e >> 10;
        const float v = w_hh[(lb*32 + jj)*NH + k];
        const int su = (jj >> 1) ^ ((k >> 6) & 15);
        smem[k*32 + su*2 + (jj & 1)] = v;
    }
    grid.sync();

    float* ghalt  = haltA + gp*768;          // [3][16][16]
    unsigned* arr = arrA + gp*512;           // [32][16]

    const int w    = tid >> 6;
    const int lane = tid & 63;
    const int rq   = w >> 2;                 // row quad 0..3
    const int co   = w & 3;                  // col octet 0..3
    const int up   = lane & 3;               // col pair in octet
    const int ks   = lane >> 2;              // k-slice 0..15 (64 wide)
    const int u    = co*4 + up;              // col pair in block 0..15
    const int jg   = lb*32 + u*2;            // global col (pair base)
    const int b0   = gp*16 + rq*4;           // first of my 4 rows
    const bool k0  = (ks == 0);
    const int ldsb = ks*2048 + ((u ^ ks) << 1);  // swizzled base, + kc*32 per k

    const float wh0 = w_halt[jg], wh1 = w_halt[jg+1];
    const float bh  = b_halt[0];
    const float bias0 = k0 ? (b_ih[jg]   + b_hh[jg])   : 0.0f;
    const float bias1 = k0 ? (b_ih[jg+1] + b_hh[jg+1]) : 0.0f;
    const float w0a   = k0 ? w_ih[jg*(NI+1)]     : 0.0f;
    const float w0b   = k0 ? w_ih[(jg+1)*(NI+1)] : 0.0f;

    // epilogue mapping: wave = row, lane = (ocol 0..15, kquarter 0..3)
    const int   eo = lb*16 + (lane & 15);
    const int   eq = lane >> 4;
    const int   eb = gp*16 + w;
    const float bo = b_out[eo];

    __shared__ float s_cum[16];
    __shared__ int   s_n[16];
    __shared__ unsigned char s_act[16];
    __shared__ int   s_cnt;
    __shared__ float s_hp[16][4];            // per-wave halt partials (4 rows)

    unsigned gen = 0;
    int g = 0;                               // step counter -> halt slot rotation
    for (int t = 0; t < NT; ++t) {
        // -------- x-part partials (per-lane, unreduced; persist over ponder) ----
        float xw[4][2];
        xw[0][0]=bias0; xw[0][1]=bias1; xw[1][0]=bias0; xw[1][1]=bias1;
        xw[2][0]=bias0; xw[2][1]=bias1; xw[3][0]=bias0; xw[3][1]=bias1;
        {
            const float* xr0 = x + ((b0+0)*NT + t)*NI + ks*32;
            const float* xr1 = x + ((b0+1)*NT + t)*NI + ks*32;
            const float* xr2 = x + ((b0+2)*NT + t)*NI + ks*32;
            const float* xr3 = x + ((b0+3)*NT + t)*NI + ks*32;
            const float* wp  = wihT + (ks*32)*NH + jg;
            #pragma unroll 4
            for (int i = 0; i < 32; i += 4) {
                const float4 x0 = *(const float4*)(xr0 + i);
                const float4 x1 = *(const float4*)(xr1 + i);
                const float4 x2 = *(const float4*)(xr2 + i);
                const float4 x3 = *(const float4*)(xr3 + i);
                const float2 wa = *(const float2*)(wp + (i  )*NH);
                const float2 wb = *(const float2*)(wp + (i+1)*NH);
                const float2 wc = *(const float2*)(wp + (i+2)*NH);
                const float2 wd = *(const float2*)(wp + (i+3)*NH);
                xw[0][0] += x0.x*wa.x + x0.y*wb.x + x0.z*wc.x + x0.w*wd.x;
                xw[0][1] += x0.x*wa.y + x0.y*wb.y + x0.z*wc.y + x0.w*wd.y;
                xw[1][0] += x1.x*wa.x + x1.y*wb.x + x1.z*wc.x + x1.w*wd.x;
                xw[1][1] += x1.x*wa.y + x1.y*wb.y + x1.z*wc.y + x1.w*wd.y;
                xw[2][0] += x2.x*wa.x + x2.y*wb.x + x2.z*wc.x + x2.w*wd.x;
                xw[2][1] += x2.x*wa.y + x2.y*wb.y + x2.z*wc.y + x2.w*wd.y;
                xw[3][0] += x3.x*wa.x + x3.y*wb.x + x3.z*wc.x + x3.w*wd.x;
                xw[3][1] += x3.x*wa.y + x3.y*wb.y + x3.z*wc.y + x3.w*wd.y;
            }
        }

        // hh matmul over this lane's 64-k slice, weights from LDS
        auto hh_matmul = [&](const float* hsrc, float a[4][2]) {
            const float* hp0 = hsrc + (b0+0)*NH + ks*64;
            const float* hp1 = hsrc + (b0+1)*NH + ks*64;
            const float* hp2 = hsrc + (b0+2)*NH + ks*64;
            const float* hp3 = hsrc + (b0+3)*NH + ks*64;
            #pragma unroll 4
            for (int kc = 0; kc < 64; kc += 4) {
                const float4 h0 = *(const float4*)(hp0 + kc);
                const float4 h1 = *(const float4*)(hp1 + kc);
                const float4 h2 = *(const float4*)(hp2 + kc);
                const float4 h3 = *(const float4*)(hp3 + kc);
                const float2 wa = *(const float2*)(smem + ldsb + (kc  )*32);
                const float2 wb = *(const float2*)(smem + ldsb + (kc+1)*32);
                const float2 wc = *(const float2*)(smem + ldsb + (kc+2)*32);
                const float2 wd = *(const float2*)(smem + ldsb + (kc+3)*32);
                a[0][0] += h0.x*wa.x + h0.y*wb.x + h0.z*wc.x + h0.w*wd.x;
                a[0][1] += h0.x*wa.y + h0.y*wb.y + h0.z*wc.y + h0.w*wd.y;
                a[1][0] += h1.x*wa.x + h1.y*wb.x + h1.z*wc.x + h1.w*wd.x;
                a[1][1] += h1.x*wa.y + h1.y*wb.y + h1.z*wc.y + h1.w*wd.y;
                a[2][0] += h2.x*wa.x + h2.y*wb.x + h2.z*wc.x + h2.w*wd.x;
                a[2][1] += h2.x*wa.y + h2.y*wb.y + h2.z*wc.y + h2.w*wd.y;
                a[3][0] += h3.x*wa.x + h3.y*wb.x + h3.z*wc.x + h3.w*wd.x;
                a[3][1] += h3.x*wa.y + h3.y*wb.y + h3.z*wc.y + h3.w*wd.y;
            }
        };
        auto reduce8 = [&](float a[4][2]) {
            #pragma unroll
            for (int r = 0; r < 4; ++r)
                #pragma unroll
                for (int c = 0; c < 2; ++c) {
                    float v = a[r][c];
                    v += __shfl_xor(v, 4);  v += __shfl_xor(v, 8);
                    v += __shfl_xor(v, 16); v += __shfl_xor(v, 32);
                    a[r][c] = v;
                }
        };

        // -------- main step --------
        {
            float a[4][2];
            a[0][0]=xw[0][0]+w0a; a[0][1]=xw[0][1]+w0b;
            a[1][0]=xw[1][0]+w0a; a[1][1]=xw[1][1]+w0b;
            a[2][0]=xw[2][0]+w0a; a[2][1]=xw[2][1]+w0b;
            a[3][0]=xw[3][0]+w0a; a[3][1]=xw[3][1]+w0b;
            const float* hc = (t == 0) ? s0 : (habuf + ((t-1)&1)*(NB*NH));
            hh_matmul(hc, a);
            reduce8(a);
            if (k0) {
                float pr[4];
                #pragma unroll
                for (int r = 0; r < 4; ++r) {
                    const float ha = tanhf(a[r][0]), hb = tanhf(a[r][1]);
                    float* hw = hbuf + (b0+r)*NH + jg;                 // slot 0
                    hw[0] = ha; hw[1] = hb;
                    float* hq = habuf + (t&1)*(NB*NH) + (b0+r)*NH + jg;
                    hq[0] = ha; hq[1] = hb;
                    pr[r] = ha*wh0 + hb*wh1;
                }
                #pragma unroll
                for (int r = 0; r < 4; ++r) {
                    pr[r] += __shfl_xor(pr[r], 1);
                    pr[r] += __shfl_xor(pr[r], 2);
                }
                if (lane == 0) {
                    s_hp[w][0]=pr[0]; s_hp[w][1]=pr[1]; s_hp[w][2]=pr[2]; s_hp[w][3]=pr[3];
                }
            }
        }
        __syncthreads();
        if (tid < 16) {   // one padded-line atomic per row per block
            const int rqq = tid >> 2, rr = tid & 3;
            const float part = s_hp[rqq*4+0][rr] + s_hp[rqq*4+1][rr]
                             + s_hp[rqq*4+2][rr] + s_hp[rqq*4+3][rr];
            atomicAdd(&ghalt[(g%3)*256 + tid*16], part);
        }
        ++gen; group_barrier(arr, lb, gen, tid);
        // -------- decision after main (identical in all 32 blocks) --------
        if (tid == 0) s_cnt = 0;
        __syncthreads();
        if (tid < 16) {
            const float z = __hip_atomic_load(&ghalt[(g%3)*256 + tid*16],
                                              __ATOMIC_RELAXED, __HIP_MEMORY_SCOPE_AGENT) + bh;
            const float p = 1.0f / (1.0f + expf(-z));
            s_cum[tid] = p;
            s_n[tid]   = 1;
            const bool a = (p < 0.99f);
            s_act[tid] = a ? 1 : 0;
            if (a) atomicAdd(&s_cnt, 1);
            if (lb == 0) out[PONDOFF + (gp*16 + tid)*NT + t] = a ? 0.0f : 2.0f;
            __hip_atomic_store(&ghalt[((g+2)%3)*256 + tid*16], 0.0f,
                               __ATOMIC_RELAXED, __HIP_MEMORY_SCOPE_AGENT);
        }
        __syncthreads();
        int any = s_cnt;
        ++g;
        // -------- ponder steps --------
        for (int s = 1; s <= 11 && any; ++s) {
            const int a0 = s_act[rq*4+0], a1 = s_act[rq*4+1];
            const int a2 = s_act[rq*4+2], a3 = s_act[rq*4+3];
            if (a0|a1|a2|a3) {
                float a[4][2];
                a[0][0]=xw[0][0]; a[0][1]=xw[0][1]; a[1][0]=xw[1][0]; a[1][1]=xw[1][1];
                a[2][0]=xw[2][0]; a[2][1]=xw[2][1]; a[3][0]=xw[3][0]; a[3][1]=xw[3][1];
                hh_matmul(hbuf + ((s-1)&1)*(NB*NH), a);
                reduce8(a);
                if (k0) {
                    float pr[4] = {0.0f, 0.0f, 0.0f, 0.0f};
                    const int am[4] = {a0, a1, a2, a3};
                    #pragma unroll
                    for (int r = 0; r < 4; ++r) {
                        if (am[r]) {
                            const float ha = tanhf(a[r][0]), hb = tanhf(a[r][1]);
                            float* hw = hbuf + (s&1)*(NB*NH) + (b0+r)*NH + jg;
                            hw[0] = ha; hw[1] = hb;
                            float* hq = habuf + (t&1)*(NB*NH) + (b0+r)*NH + jg;
                            hq[0] += ha; hq[1] += hb;
                            pr[r] = ha*wh0 + hb*wh1;
                        }
                    }
                    #pragma unroll
                    for (int r = 0; r < 4; ++r) {
                        pr[r] += __shfl_xor(pr[r], 1);
                        pr[r] += __shfl_xor(pr[r], 2);
                    }
                    if (lane == 0) {
                        s_hp[w][0]=pr[0]; s_hp[w][1]=pr[1]; s_hp[w][2]=pr[2]; s_hp[w][3]=pr[3];
                    }
                }
            } else if (k0 && lane == 0) {
                s_hp[w][0]=0.0f; s_hp[w][1]=0.0f; s_hp[w][2]=0.0f; s_hp[w][3]=0.0f;
            }
            __syncthreads();
            if (tid < 16 && s_act[tid]) {
                const int rqq = tid >> 2, rr = tid & 3;
                const float part = s_hp[rqq*4+0][rr] + s_hp[rqq*4+1][rr]
                                 + s_hp[rqq*4+2][rr] + s_hp[rqq*4+3][rr];
                atomicAdd(&ghalt[(g%3)*256 + tid*16], part);
            }
            ++gen; group_barrier(arr, lb, gen, tid);
            if (tid == 0) s_cnt = 0;
            __syncthreads();
            if (tid < 16) {
                if (s_act[tid]) {
                    const float z = __hip_atomic_load(&ghalt[(g%3)*256 + tid*16],
                                                      __ATOMIC_RELAXED, __HIP_MEMORY_SCOPE_AGENT) + bh;
                    const float p = 1.0f / (1.0f + expf(-z));
                    const float c = s_cum[tid] + p;
                    s_cum[tid] = c;
                    s_n[tid] += 1;
                    s_act[tid] = (c < 0.99f) ? 1 : 0;
                }
                if (s_act[tid]) atomicAdd(&s_cnt, 1);
                __hip_atomic_store(&ghalt[((g+2)%3)*256 + tid*16], 0.0f,
                                   __ATOMIC_RELAXED, __HIP_MEMORY_SCOPE_AGENT);
            }
            __syncthreads();
            any = s_cnt;
            ++g;
        }
        // -------- epilogue: out = h_acc @ W_out^T + n*b_out (reads w_out direct) ----
        {
            const float* ha = habuf + (t&1)*(NB*NH) + eb*NH + eq*256;
            const float* wq = w_out + eo*NH + eq*256;
            float acc = 0.0f;
            #pragma unroll 4
            for (int jj2 = 0; jj2 < 256; jj2 += 4) {
                const float4 hv = *(const float4*)(ha + jj2);
                const float4 wv = *(const float4*)(wq + jj2);
                acc += hv.x*wv.x + hv.y*wv.y + hv.z*wv.z + hv.w*wv.w;
            }
            acc += __shfl_xor(acc, 16); acc += __shfl_xor(acc, 32);
            if (eq == 0) out[(eb*NT + t)*NO + eo] = acc + (float)s_n[w]*bo;
        }
        // no barrier needed before next timestep: next main writes habuf other
        // parity + hbuf slot 0 (nothing reads them until after next barrier);
        // 3-slot halt rotation keeps adds/zeros a barrier apart.
    }
}

extern "C" void kernel_launch(void* const* d_in, const int* in_sizes, int n_in,
                              void* d_out, int out_size, void* d_ws, size_t ws_size,
                              hipStream_t stream) {
    const float* x      = (const float*)d_in[0];
    const float* s0     = (const float*)d_in[1];
    const float* w_ih   = (const float*)d_in[2];
    const float* w_hh   = (const float*)d_in[3];
    const float* b_ih   = (const float*)d_in[4];
    const float* b_hh   = (const float*)d_in[5];
    const float* w_halt = (const float*)d_in[6];
    const float* b_halt = (const float*)d_in[7];
    const float* w_out  = (const float*)d_in[8];
    const float* b_out  = (const float*)d_in[9];
    float* out = (float*)d_out;
    float* ws  = (float*)d_ws;

    // 128 KB dynamic LDS needs the opt-in attribute (idempotent, host-only,
    // graph-capture safe: no stream operation involved)
    static const int kLds = 131072;
    hipFuncSetAttribute((const void*)arnn_coop,
                        hipFuncAttributeMaxDynamicSharedMemorySize, kLds);

    void* args[] = { (void*)&x, (void*)&s0, (void*)&w_ih, (void*)&w_hh,
                     (void*)&b_ih, (void*)&b_hh, (void*)&w_halt, (void*)&b_halt,
                     (void*)&w_out, (void*)&b_out, (void*)&out, (void*)&ws };
    hipLaunchCooperativeKernel((void*)arnn_coop, dim3(256), dim3(1024), args, kLds, stream);
}